// Round 3
// baseline (4498.964 us; speedup 1.0000x reference)
//
#include <hip/hip_runtime.h>
#include <stdint.h>

// ---------------------------------------------------------------------------
// TransformerBlock on MI355X (gfx950) — per-batch pipeline, small workspace.
// fp32 in/out, internally error-compensated bf16 ("3xBF16" split) on MFMA:
//   x = hi + lo (bf16);  A@B ~= Ah@Bh + Ah@Bl + Al@Bh   (rel err ~2^-17)
// GEMM B-operands stored [N][K] (k-contiguous). LDS tiles pack hi|lo in a
// 128B row of 8x16B slots, XOR-swizzled (slot ^= row&7) via pre-swizzled
// global source addresses (global_load_lds writes linearly: base + lane*16).
//
// Batch-chunked dataflow (4 sequences processed serially; attention only
// couples rows within one sequence, everything else is row-wise), so the
// arena peaks at 176 MB instead of 400 MB:
//   S [0,64)    weight-transpose scratch (E*E weights use [0,16); w1/w2 all)
//   A [64,80)   h1b hi/lo      -> ctxb hi/lo
//   B [80,96)   qb hi/lo       -> x2b fp32
//   C [96,112)  kb hi/lo       -> h2b hi/lo
//   D [112,128) vb fp32        -+-> h3b hi [112,144)
//   E [128,144) vTb hi/lo      -+   h3b lo [144,176)
// ---------------------------------------------------------------------------

#define EMBED 2048
#define SEQ   2048
#define BATCH 4
#define FFDIM 8192
#define HEADS 16
#define HD    128

typedef unsigned short ushort_t;
typedef float f32x4 __attribute__((ext_vector_type(4)));
typedef short s16x8 __attribute__((ext_vector_type(8)));

__device__ __forceinline__ ushort_t f2bf(float f) {
  unsigned u = __builtin_bit_cast(unsigned, f);
  u += 0x7fffu + ((u >> 16) & 1u);          // RNE (NaN irrelevant here)
  return (ushort_t)(u >> 16);
}
__device__ __forceinline__ float bf2f(ushort_t h) {
  unsigned u = ((unsigned)h) << 16;
  return __builtin_bit_cast(float, u);
}
__device__ __forceinline__ void split2(float f, ushort_t& hi, ushort_t& lo) {
  hi = f2bf(f);
  lo = f2bf(f - bf2f(hi));
}

#define MFMA16(a,b,c) __builtin_amdgcn_mfma_f32_16x16x32_bf16((a),(b),(c),0,0,0)

__device__ __forceinline__ void gload16(const void* g, void* l) {
  __builtin_amdgcn_global_load_lds((const __attribute__((address_space(1))) void*)g,
                                   (__attribute__((address_space(3))) void*)l,
                                   16, 0, 0);
}

// --------------------------- LayerNorm -> hi/lo ----------------------------
__global__ __launch_bounds__(256)
void ln_split(const float* __restrict__ x, const float* __restrict__ sc,
              const float* __restrict__ sh, ushort_t* __restrict__ hi,
              ushort_t* __restrict__ lo)
{
  __shared__ float rs[4], rq[4];
  const int row = blockIdx.x, t = threadIdx.x;
  const int lane = t & 63, w = t >> 6;
  const float* xr = x + (size_t)row * EMBED;
  f32x4 a = *(const f32x4*)(xr + t*4);
  f32x4 b = *(const f32x4*)(xr + 1024 + t*4);
  float s = 0.f, q = 0.f;
  #pragma unroll
  for (int e=0;e<4;++e){ s += a[e]+b[e]; q += a[e]*a[e]+b[e]*b[e]; }
  #pragma unroll
  for (int m=1;m<64;m<<=1){ s += __shfl_xor(s,m,64); q += __shfl_xor(q,m,64); }
  if (lane==0){ rs[w]=s; rq[w]=q; }
  __syncthreads();
  s = rs[0]+rs[1]+rs[2]+rs[3];
  q = rq[0]+rq[1]+rq[2]+rq[3];
  const float mean = s * (1.f/EMBED);
  const float var  = fmaxf(q*(1.f/EMBED) - mean*mean, 0.f);
  const float rstd = rsqrtf(var + 1e-5f);
  #pragma unroll
  for (int half=0; half<2; ++half) {
    const int c0 = half*1024 + t*4;
    f32x4 v = half ? b : a;
    #pragma unroll
    for (int e=0;e<4;++e) {
      float o = sc[c0+e]*((v[e]-mean)*rstd) + sh[c0+e];
      ushort_t hh, ll; split2(o, hh, ll);
      hi[(size_t)row*EMBED + c0+e] = hh;
      lo[(size_t)row*EMBED + c0+e] = ll;
    }
  }
}

// ----------------- W [K][N] fp32 -> W^T [N][K] hi/lo bf16 ------------------
__global__ __launch_bounds__(256)
void wtrans_split(const float* __restrict__ W, int K, int N,
                  ushort_t* __restrict__ Thi, ushort_t* __restrict__ Tlo)
{
  __shared__ float tile[32][33];
  const int n0 = blockIdx.x*32, k0 = blockIdx.y*32;
  const int tx = threadIdx.x & 31, ty = threadIdx.x >> 5;
  #pragma unroll
  for (int i=0;i<4;++i)
    tile[ty + i*8][tx] = W[(size_t)(k0 + ty + i*8)*N + n0 + tx];
  __syncthreads();
  #pragma unroll
  for (int i=0;i<4;++i) {
    const int nl = ty + i*8;
    float v = tile[tx][nl];
    ushort_t h, l; split2(v, h, l);
    const size_t idx = (size_t)(n0 + nl)*K + k0 + tx;
    Thi[idx] = h; Tlo[idx] = l;
  }
}

// ---- per-batch v fp32 [S][EMBED] -> v^T hi/lo [(h*HD+d)][s] ---------------
__global__ __launch_bounds__(256)
void vtrans_split(const float* __restrict__ V, ushort_t* __restrict__ hi,
                  ushort_t* __restrict__ lo)
{
  __shared__ float tile[32][33];
  const int hh_ = blockIdx.z;                // head index within the batch
  const int s0 = blockIdx.x*32, d0 = blockIdx.y*32;
  const int tx = threadIdx.x & 31, ty = threadIdx.x >> 5;
  #pragma unroll
  for (int i=0;i<4;++i)
    tile[ty + i*8][tx] = V[(size_t)(s0 + ty + i*8)*EMBED + hh_*HD + d0 + tx];
  __syncthreads();
  #pragma unroll
  for (int i=0;i<4;++i) {
    const int dl = ty + i*8;
    float v = tile[tx][dl];
    ushort_t h, l; split2(v, h, l);
    const size_t idx = (size_t)(hh_*HD + d0 + dl)*SEQ + s0 + tx;
    hi[idx] = h; lo[idx] = l;
  }
}

// ------------------------------ split GEMM ---------------------------------
// C[M,N] = A[M,K] @ B^T  (B stored [N][K]), 3-term bf16 split, fp32 acc.
// Tile 128x128, BK=32, 256 thr (4 waves 2x2, each 64x64 = 4x4 16x16 frags).
// LDS row (per tile row r): 8 slots of 16B: slots 0-3 = hi k0..31, 4-7 = lo,
// physically stored at slot ^ (r&7)  (2-way-max ds_read_b128, free).
// EPI: 0 = write hi/lo bf16; 1 = write fp32; 2 = resid + bias -> fp32;
//      3 = gelu(v+bias) -> hi/lo bf16.
template<int EPI>
__global__ __launch_bounds__(256, 2)
void gemm_split(const ushort_t* __restrict__ Ahi, const ushort_t* __restrict__ Alo,
                const ushort_t* __restrict__ Bhi, const ushort_t* __restrict__ Blo,
                int M, int N, int K,
                float* __restrict__ outf,
                ushort_t* __restrict__ ohi, ushort_t* __restrict__ olo,
                const float* __restrict__ bias, const float* __restrict__ resid)
{
  __shared__ __align__(16) char lds[32768];   // A tile 16KB @0, B tile @16384
  const int t = threadIdx.x, lane = t & 63;
  const int wid = t >> 6;
  const int l15 = lane & 15, g = lane >> 4;
  const int row0 = blockIdx.x * 128, col0 = blockIdx.y * 128;
  const int wm = (wid >> 1) * 64, wn = (wid & 1) * 64;
  f32x4 acc[4][4] = {};
  for (int k0 = 0; k0 < K; k0 += 32) {
    #pragma unroll
    for (int i=0;i<4;++i) {
      const int qq = i*256 + t;                 // 0..1023 -> 16KB tile
      const unsigned o = (unsigned)qq*16u;
      const int r = o >> 7, sp = (o >> 4) & 7;
      const int sd = sp ^ (r & 7);              // logical slot stored here
      const size_t koff = (size_t)k0 + (sd & 3)*8;
      const ushort_t* srcA = ((sd<4)?Ahi:Alo) + (size_t)(row0+r)*K + koff;
      const ushort_t* srcB = ((sd<4)?Bhi:Blo) + (size_t)(col0+r)*K + koff;
      char* du = lds + (o - (unsigned)lane*16u);  // wave-uniform base
      gload16(srcA, du);
      gload16(srcB, du + 16384);
    }
    __syncthreads();
    s16x8 ah[4], al_[4], bh[4], bl[4];
    #pragma unroll
    for (int mf=0; mf<4; ++mf) {
      const int r = wm + mf*16 + l15;
      const char* rp = lds + r*128;
      ah[mf]  = *(const s16x8*)(rp + ((g ^ (r&7))*16));
      al_[mf] = *(const s16x8*)(rp + (((4|g) ^ (r&7))*16));
    }
    #pragma unroll
    for (int nf=0; nf<4; ++nf) {
      const int r = wn + nf*16 + l15;
      const char* rp = lds + 16384 + r*128;
      bh[nf] = *(const s16x8*)(rp + ((g ^ (r&7))*16));
      bl[nf] = *(const s16x8*)(rp + (((4|g) ^ (r&7))*16));
    }
    #pragma unroll
    for (int mf=0; mf<4; ++mf)
      #pragma unroll
      for (int nf=0; nf<4; ++nf) {
        f32x4 c = acc[mf][nf];
        c = MFMA16(ah[mf],  bh[nf], c);
        c = MFMA16(ah[mf],  bl[nf], c);
        c = MFMA16(al_[mf], bh[nf], c);
        acc[mf][nf] = c;
      }
    __syncthreads();
  }
  #pragma unroll
  for (int mf=0; mf<4; ++mf) {
    const int rr = row0 + wm + mf*16 + g*4;
    #pragma unroll
    for (int nf=0; nf<4; ++nf) {
      const int cc = col0 + wn + nf*16 + l15;
      #pragma unroll
      for (int j=0;j<4;++j) {
        const size_t idx = (size_t)(rr+j)*N + cc;
        float v = acc[mf][nf][j];
        if constexpr (EPI == 0) {
          ushort_t hh, ll; split2(v, hh, ll);
          ohi[idx]=hh; olo[idx]=ll;
        } else if constexpr (EPI == 1) {
          outf[idx] = v;
        } else if constexpr (EPI == 2) {
          outf[idx] = resid[idx] + v + bias[cc];
        } else {
          float u = v + bias[cc];
          float gg = 0.5f*u*(1.0f + tanhf(0.7978845608028654f*(u + 0.044715f*u*u*u)));
          ushort_t hh, ll; split2(gg, hh, ll);
          ohi[idx]=hh; olo[idx]=ll;
        }
      }
    }
  }
}

// ---------------------------- flash attention ------------------------------
// Per-batch: grid (qb=16, head=16), 512 thr (8 waves x 16 q-rows).
// QBLK=128, KVBLK=64. Q/K/C pointers are batch-relative ([SEQ][EMBED] rows).
// K tile LDS: [64][256B] (16 slots, low-3-bit XOR swizzle), hi @0, lo @16384.
// V^T tile:   [128][128B] (8 slots, XOR swizzle),           hi @32768, lo @49152.
__global__ __launch_bounds__(512)
void attn_fwd(const ushort_t* __restrict__ Qhi, const ushort_t* __restrict__ Qlo,
              const ushort_t* __restrict__ Khi, const ushort_t* __restrict__ Klo,
              const ushort_t* __restrict__ VThi, const ushort_t* __restrict__ VTlo,
              ushort_t* __restrict__ Chi, ushort_t* __restrict__ Clo)
{
  __shared__ __align__(16) char kv[65536];
  __shared__ __align__(16) float plds[8][16][68];  // per-wave P scratch (pad 68)
  const int qb = blockIdx.x, slab = blockIdx.y;    // slab = head (bb folded out)
  const int hh_ = slab & 15;
  const int t = threadIdx.x, lane = t & 63, w = t >> 6;
  const int l15 = lane & 15, g = lane >> 4;
  const int qrow = qb*128 + w*16 + l15;
  const size_t qbase = (size_t)qrow*EMBED + hh_*HD;
  s16x8 qh[4], ql[4];
  #pragma unroll
  for (int ks=0; ks<4; ++ks) {
    qh[ks] = *(const s16x8*)(Qhi + qbase + ks*32 + g*8);
    ql[ks] = *(const s16x8*)(Qlo + qbase + ks*32 + g*8);
  }
  f32x4 ctx[8] = {};
  float ms[4], ls[4];
  #pragma unroll
  for (int j=0;j<4;++j){ ms[j] = -__builtin_inff(); ls[j] = 0.f; }
  const int ntiles = qb*2 + 2;
  const float scale = 0.08838834764831844f;   // 1/sqrt(128)
  for (int kt=0; kt<ntiles; ++kt) {
    { // stage K tile (hi/lo) + V^T tile (hi/lo)
      const size_t kbase = (size_t)(kt*64)*EMBED + hh_*HD;
      #pragma unroll
      for (int i=0;i<2;++i) {
        const int qq = i*512 + t;
        const unsigned o = (unsigned)qq*16u;
        const int r = o >> 8, sp = (o >> 4) & 15;
        const int sd = (sp & 8) | ((sp & 7) ^ (r & 7));
        char* du = kv + (o - (unsigned)lane*16u);
        gload16(Khi + kbase + (size_t)r*EMBED + sd*8, du);
        gload16(Klo + kbase + (size_t)r*EMBED + sd*8, du + 16384);
      }
      const size_t vbase = (size_t)slab*HD*SEQ + (size_t)kt*64;
      #pragma unroll
      for (int i=0;i<2;++i) {
        const int qq = i*512 + t;
        const unsigned o = (unsigned)qq*16u;
        const int r = o >> 7, sp = (o >> 4) & 7;
        const int sd = sp ^ (r & 7);
        char* du = kv + 32768 + (o - (unsigned)lane*16u);
        gload16(VThi + vbase + (size_t)r*SEQ + sd*8, du);
        gload16(VTlo + vbase + (size_t)r*SEQ + sd*8, du + 16384);
      }
    }
    __syncthreads();
    // QK^T (3-term split)
    f32x4 sc[4];
    #pragma unroll
    for (int nf=0; nf<4; ++nf) {
      f32x4 s = {};
      const int rB = nf*16 + l15;
      const char* rp = kv + rB*256;
      #pragma unroll
      for (int ks=0; ks<4; ++ks) {
        const int slot = ks*4 + g;
        const int ph = (slot & 8) | ((slot & 7) ^ (rB & 7));
        s16x8 kbh = *(const s16x8*)(rp + ph*16);
        s16x8 kbl = *(const s16x8*)(rp + 16384 + ph*16);
        s = MFMA16(qh[ks], kbh, s);
        s = MFMA16(qh[ks], kbl, s);
        s = MFMA16(ql[ks], kbh, s);
      }
      sc[nf] = s;
    }
    // scale + causal mask (C/D layout: col = l15, row = g*4+j)
    const int rowq = qb*128 + w*16 + g*4;
    #pragma unroll
    for (int nf=0; nf<4; ++nf) {
      const int col = kt*64 + nf*16 + l15;
      #pragma unroll
      for (int j=0;j<4;++j) {
        float v = sc[nf][j]*scale;
        sc[nf][j] = (col > rowq + j) ? -__builtin_inff() : v;
      }
    }
    // online softmax (rows on g*4+j; reduce over l15 = lane bits 0..3)
    float tm[4], al[4], mnu[4], ts[4];
    #pragma unroll
    for (int j=0;j<4;++j) {
      float m = fmaxf(fmaxf(sc[0][j], sc[1][j]), fmaxf(sc[2][j], sc[3][j]));
      #pragma unroll
      for (int d=1; d<16; d<<=1) m = fmaxf(m, __shfl_xor(m, d, 64));
      tm[j] = m;
    }
    #pragma unroll
    for (int j=0;j<4;++j) {
      const float mo = ms[j];
      const float mn = fmaxf(mo, tm[j]);
      const float mu = fmaxf(mn, -1e30f);     // guard -inf - -inf
      al[j] = expf(mo - mu);
      mnu[j] = mu; ms[j] = mn; ts[j] = 0.f;
    }
    #pragma unroll
    for (int nf=0; nf<4; ++nf)
      #pragma unroll
      for (int j=0;j<4;++j) {
        float p = expf(sc[nf][j] - mnu[j]);
        sc[nf][j] = p;
        ts[j] += p;
      }
    #pragma unroll
    for (int j=0;j<4;++j) {
      #pragma unroll
      for (int d=1; d<16; d<<=1) ts[j] += __shfl_xor(ts[j], d, 64);
      ls[j] = ls[j]*al[j] + ts[j];
    }
    #pragma unroll
    for (int nf2=0; nf2<8; ++nf2)
      #pragma unroll
      for (int j=0;j<4;++j) ctx[nf2][j] *= al[j];
    // P -> LDS (transpose to A-frag layout), wave-private region.
    #pragma unroll
    for (int nf=0; nf<4; ++nf)
      #pragma unroll
      for (int j=0;j<4;++j)
        plds[w][g*4+j][nf*16+l15] = sc[nf][j];
    asm volatile("s_waitcnt lgkmcnt(0)" ::: "memory");
    __builtin_amdgcn_sched_barrier(0);
    // PV (3-term split)
    #pragma unroll
    for (int ks2=0; ks2<2; ++ks2) {
      const float* pr = &plds[w][l15][ks2*32 + g*8];
      f32x4 p0 = *(const f32x4*)pr;
      f32x4 p1 = *(const f32x4*)(pr + 4);
      s16x8 ph8, pl8;
      #pragma unroll
      for (int e=0;e<4;++e) {
        ushort_t h1_, l1_; split2(p0[e], h1_, l1_);
        ph8[e] = (short)h1_; pl8[e] = (short)l1_;
        ushort_t h2_, l2_; split2(p1[e], h2_, l2_);
        ph8[e+4] = (short)h2_; pl8[e+4] = (short)l2_;
      }
      #pragma unroll
      for (int nf2=0; nf2<8; ++nf2) {
        const int rV = nf2*16 + l15;
        const int ph_ = (ks2*4 + g) ^ (rV & 7);
        const char* vp = kv + 32768 + rV*128 + ph_*16;
        s16x8 vbh = *(const s16x8*)vp;
        s16x8 vbl = *(const s16x8*)(vp + 16384);
        ctx[nf2] = MFMA16(ph8, vbh, ctx[nf2]);
        ctx[nf2] = MFMA16(ph8, vbl, ctx[nf2]);
        ctx[nf2] = MFMA16(pl8, vbh, ctx[nf2]);
      }
    }
    __syncthreads();
  }
  float rl[4];
  #pragma unroll
  for (int j=0;j<4;++j) rl[j] = 1.f / ls[j];
  #pragma unroll
  for (int nf2=0; nf2<8; ++nf2) {
    #pragma unroll
    for (int j=0;j<4;++j) {
      float v = ctx[nf2][j]*rl[j];
      const size_t idx = (size_t)(qb*128 + w*16 + g*4 + j)*EMBED
                       + hh_*HD + nf2*16 + l15;
      ushort_t hh, ll; split2(v, hh, ll);
      Chi[idx] = hh; Clo[idx] = ll;
    }
  }
}

// ------------------------------- launcher ----------------------------------
extern "C" void kernel_launch(void* const* d_in, const int* in_sizes, int n_in,
                              void* d_out, int out_size, void* d_ws, size_t ws_size,
                              hipStream_t stream)
{
  (void)in_sizes; (void)n_in; (void)out_size; (void)ws_size;
  const float* x    = (const float*)d_in[0];
  const float* wq   = (const float*)d_in[1];
  const float* wk   = (const float*)d_in[2];
  const float* wv   = (const float*)d_in[3];
  const float* wo   = (const float*)d_in[4];
  const float* bo   = (const float*)d_in[5];
  const float* w1   = (const float*)d_in[6];
  const float* b1   = (const float*)d_in[7];
  const float* w2   = (const float*)d_in[8];
  const float* b2   = (const float*)d_in[9];
  const float* ln1s = (const float*)d_in[10];
  const float* ln1h = (const float*)d_in[11];
  const float* ln2s = (const float*)d_in[12];
  const float* ln2h = (const float*)d_in[13];

  char* ws = (char*)d_ws;
  const size_t MB = 1ull << 20;
  // S [0,64): weight-transpose scratch
  ushort_t* wT_hi  = (ushort_t*)(ws +   0*MB);   // E*E weights: hi 8MB
  ushort_t* wT_lo  = (ushort_t*)(ws +   8*MB);   //              lo 8MB
  ushort_t* wfT_hi = (ushort_t*)(ws +   0*MB);   // w1/w2: hi 32MB
  ushort_t* wfT_lo = (ushort_t*)(ws +  32*MB);   //        lo 32MB
  // A [64,80): h1b -> ctxb
  ushort_t* h1_hi  = (ushort_t*)(ws +  64*MB);
  ushort_t* h1_lo  = (ushort_t*)(ws +  72*MB);
  ushort_t* ctx_hi = h1_hi;                      // h1 dead after QKV proj
  ushort_t* ctx_lo = h1_lo;
  // B [80,96): qb -> x2b fp32
  ushort_t* q_hi   = (ushort_t*)(ws +  80*MB);
  ushort_t* q_lo   = (ushort_t*)(ws +  88*MB);
  float*    x2     = (float*)   (ws +  80*MB);   // q dead after attn
  // C [96,112): kb -> h2b
  ushort_t* k_hi   = (ushort_t*)(ws +  96*MB);
  ushort_t* k_lo   = (ushort_t*)(ws + 104*MB);
  ushort_t* h2_hi  = k_hi;                       // k dead after attn
  ushort_t* h2_lo  = k_lo;
  // D [112,128): vb fp32 ; E [128,144): vTb hi/lo
  float*    vf     = (float*)   (ws + 112*MB);
  ushort_t* vt_hi  = (ushort_t*)(ws + 128*MB);
  ushort_t* vt_lo  = (ushort_t*)(ws + 136*MB);
  // F: h3b split (v/vT dead after attn): hi [112,144), lo [144,176)
  ushort_t* h3_hi  = (ushort_t*)(ws + 112*MB);
  ushort_t* h3_lo  = (ushort_t*)(ws + 144*MB);

  for (int b = 0; b < BATCH; ++b) {
    const size_t ro = (size_t)b * SEQ * EMBED;   // batch row offset (elements)
    const float* xb = x + ro;

    // LN1 -> h1b
    ln_split<<<SEQ, 256, 0, stream>>>(xb, ln1s, ln1h, h1_hi, h1_lo);

    // q/k/v projections (weight transposed into scratch before each)
    wtrans_split<<<dim3(64,64), 256, 0, stream>>>(wq, EMBED, EMBED, wT_hi, wT_lo);
    gemm_split<0><<<dim3(16,16), 256, 0, stream>>>(h1_hi, h1_lo, wT_hi, wT_lo,
        SEQ, EMBED, EMBED, nullptr, q_hi, q_lo, nullptr, nullptr);
    wtrans_split<<<dim3(64,64), 256, 0, stream>>>(wk, EMBED, EMBED, wT_hi, wT_lo);
    gemm_split<0><<<dim3(16,16), 256, 0, stream>>>(h1_hi, h1_lo, wT_hi, wT_lo,
        SEQ, EMBED, EMBED, nullptr, k_hi, k_lo, nullptr, nullptr);
    wtrans_split<<<dim3(64,64), 256, 0, stream>>>(wv, EMBED, EMBED, wT_hi, wT_lo);
    gemm_split<1><<<dim3(16,16), 256, 0, stream>>>(h1_hi, h1_lo, wT_hi, wT_lo,
        SEQ, EMBED, EMBED, vf, nullptr, nullptr, nullptr, nullptr);

    // v -> v^T hi/lo (per-head, batch-relative)
    vtrans_split<<<dim3(64,4,16), 256, 0, stream>>>(vf, vt_hi, vt_lo);

    // causal flash attention -> ctxb (overwrites h1b, dead)
    attn_fwd<<<dim3(16,16), 512, 0, stream>>>(q_hi, q_lo, k_hi, k_lo,
                                              vt_hi, vt_lo, ctx_hi, ctx_lo);

    // x2b = xb + ctxb@wo + bo   (overwrites qb, dead)
    wtrans_split<<<dim3(64,64), 256, 0, stream>>>(wo, EMBED, EMBED, wT_hi, wT_lo);
    gemm_split<2><<<dim3(16,16), 256, 0, stream>>>(ctx_hi, ctx_lo, wT_hi, wT_lo,
        SEQ, EMBED, EMBED, x2, nullptr, nullptr, bo, xb);

    // LN2 -> h2b (overwrites kb, dead)
    ln_split<<<SEQ, 256, 0, stream>>>(x2, ln2s, ln2h, h2_hi, h2_lo);

    // h3b = gelu(h2b@w1 + b1)  (overwrites v/vT region, dead)
    wtrans_split<<<dim3(256,64), 256, 0, stream>>>(w1, EMBED, FFDIM, wfT_hi, wfT_lo);
    gemm_split<3><<<dim3(16,64), 256, 0, stream>>>(h2_hi, h2_lo, wfT_hi, wfT_lo,
        SEQ, FFDIM, EMBED, nullptr, h3_hi, h3_lo, b1, nullptr);

    // out_b = x2b + h3b@w2 + b2
    wtrans_split<<<dim3(64,256), 256, 0, stream>>>(w2, FFDIM, EMBED, wfT_hi, wfT_lo);
    gemm_split<2><<<dim3(16,16), 256, 0, stream>>>(h3_hi, h3_lo, wfT_hi, wfT_lo,
        SEQ, EMBED, FFDIM, (float*)d_out + ro, nullptr, nullptr, b2, x2);
  }
}

// Round 4
// 3476.906 us; speedup vs baseline: 1.2940x; 1.2940x over previous
//
#include <hip/hip_runtime.h>
#include <stdint.h>

// ---------------------------------------------------------------------------
// TransformerBlock on MI355X (gfx950) — R4: dbuf-prefetch GEMM + big grids.
// fp32 in/out, error-compensated bf16 ("3xBF16" split) on MFMA:
//   x = hi + lo (bf16);  A@B ~= Ah@Bh + Ah@Bl + Al@Bh   (rel err ~2^-17)
// GEMM B-operands stored [N][K] (k-contiguous). LDS rows pack hi|lo in 8x16B
// slots XOR-swizzled (slot ^= row&7) via pre-swizzled global sources
// (global_load_lds writes linearly). GEMM K-loop: double-buffered LDS,
// STAGE(t+1) issued before compute(t), one __syncthreads per iter.
//
// Arena (<=176 MB, proven good):
//  phase A (attn):  [0,48) wqkvT | [48,64) woT | [64,128) h1->ctx |
//                   [128,160) qk (stride 6144? no: 4096) | [160,176) vT
//  phase B (ffn):   [0,64) h2 | [64,128) h3 chunk | [128,144) w1Tc/w2Tc
//  x2 lives in d_out (O-proj writes, LN2 reads, FFN2 accumulates in-place).
// ---------------------------------------------------------------------------

#define EMBED 2048
#define SEQ   2048
#define BATCH 4
#define NROWS (BATCH*SEQ)
#define FFDIM 8192
#define HEADS 16
#define HD    128
#define QKS   4096   // row stride of fused q|k buffer

typedef unsigned short ushort_t;
typedef float f32x4 __attribute__((ext_vector_type(4)));
typedef short s16x8 __attribute__((ext_vector_type(8)));
typedef ushort_t u16x4 __attribute__((ext_vector_type(4)));

__device__ __forceinline__ ushort_t f2bf(float f) {
  unsigned u = __builtin_bit_cast(unsigned, f);
  u += 0x7fffu + ((u >> 16) & 1u);
  return (ushort_t)(u >> 16);
}
__device__ __forceinline__ float bf2f(ushort_t h) {
  unsigned u = ((unsigned)h) << 16;
  return __builtin_bit_cast(float, u);
}
__device__ __forceinline__ void split2(float f, ushort_t& hi, ushort_t& lo) {
  hi = f2bf(f);
  lo = f2bf(f - bf2f(hi));
}

#define MFMA16(a,b,c) __builtin_amdgcn_mfma_f32_16x16x32_bf16((a),(b),(c),0,0,0)

__device__ __forceinline__ void gload16(const void* g, void* l) {
  __builtin_amdgcn_global_load_lds((const __attribute__((address_space(1))) void*)g,
                                   (__attribute__((address_space(3))) void*)l,
                                   16, 0, 0);
}

// --------------------------- LayerNorm -> hi/lo ----------------------------
__global__ __launch_bounds__(256)
void ln_split(const float* __restrict__ x, const float* __restrict__ sc,
              const float* __restrict__ sh, ushort_t* __restrict__ hi,
              ushort_t* __restrict__ lo)
{
  __shared__ float rs[4], rq[4];
  const int row = blockIdx.x, t = threadIdx.x;
  const int lane = t & 63, w = t >> 6;
  const float* xr = x + (size_t)row * EMBED;
  f32x4 a = *(const f32x4*)(xr + t*4);
  f32x4 b = *(const f32x4*)(xr + 1024 + t*4);
  float s = 0.f, q = 0.f;
  #pragma unroll
  for (int e=0;e<4;++e){ s += a[e]+b[e]; q += a[e]*a[e]+b[e]*b[e]; }
  #pragma unroll
  for (int m=1;m<64;m<<=1){ s += __shfl_xor(s,m,64); q += __shfl_xor(q,m,64); }
  if (lane==0){ rs[w]=s; rq[w]=q; }
  __syncthreads();
  s = rs[0]+rs[1]+rs[2]+rs[3];
  q = rq[0]+rq[1]+rq[2]+rq[3];
  const float mean = s * (1.f/EMBED);
  const float var  = fmaxf(q*(1.f/EMBED) - mean*mean, 0.f);
  const float rstd = rsqrtf(var + 1e-5f);
  #pragma unroll
  for (int half=0; half<2; ++half) {
    const int c0 = half*1024 + t*4;
    f32x4 v = half ? b : a;
    #pragma unroll
    for (int e=0;e<4;++e) {
      float o = sc[c0+e]*((v[e]-mean)*rstd) + sh[c0+e];
      ushort_t hh, ll; split2(o, hh, ll);
      hi[(size_t)row*EMBED + c0+e] = hh;
      lo[(size_t)row*EMBED + c0+e] = ll;
    }
  }
}

// ------- W (k,n) at W[k*ldW+n] -> T [n][K] hi/lo bf16; grid (N/32, K/32) ----
__global__ __launch_bounds__(256)
void wtrans_split(const float* __restrict__ W, int ldW, int K,
                  ushort_t* __restrict__ Thi, ushort_t* __restrict__ Tlo)
{
  __shared__ float tile[32][33];
  const int n0 = blockIdx.x*32, k0 = blockIdx.y*32;
  const int tx = threadIdx.x & 31, ty = threadIdx.x >> 5;
  #pragma unroll
  for (int i=0;i<4;++i)
    tile[ty + i*8][tx] = W[(size_t)(k0 + ty + i*8)*ldW + n0 + tx];
  __syncthreads();
  #pragma unroll
  for (int i=0;i<4;++i) {
    const int nl = ty + i*8;
    float v = tile[tx][nl];
    ushort_t h, l; split2(v, h, l);
    const size_t idx = (size_t)(n0 + nl)*K + k0 + tx;
    Thi[idx] = h; Tlo[idx] = l;
  }
}

// ------------------------------ split GEMM ---------------------------------
// C[M,N] = A[M,K] @ B^T (B stored [N][K]), 3-term bf16 split, fp32 acc.
// Tile 128x128, BK=32, 256 thr (4 waves 2x2, 64x64 each). Double-buffered LDS
// (2 x 32KB), STAGE(next) issued before compute(cur), one barrier per iter.
// EPI: 2 = resid+bias -> fp32; 3 = gelu(v+bias) -> hi/lo bf16;
//      4 = resid (no bias) -> fp32; 5 = QKV fused (qk strided / v transposed).
template<int EPI>
__global__ __launch_bounds__(256, 2)
void gemm_split(const ushort_t* __restrict__ Ahi, const ushort_t* __restrict__ Alo,
                const ushort_t* __restrict__ Bhi, const ushort_t* __restrict__ Blo,
                int M, int N, int K,
                float* __restrict__ outf,
                ushort_t* __restrict__ ohi, ushort_t* __restrict__ olo,
                ushort_t* __restrict__ ohi2, ushort_t* __restrict__ olo2,
                const float* __restrict__ bias, const float* __restrict__ resid)
{
  __shared__ __align__(16) char lds[65536];  // buf0 @0 (A 16K, B 16K), buf1 @32768
  const int t = threadIdx.x, lane = t & 63;
  const int wid = t >> 6;
  const int l15 = lane & 15, g = lane >> 4;
  const int row0 = blockIdx.x * 128, col0 = blockIdx.y * 128;
  const int wm = (wid >> 1) * 64, wn = (wid & 1) * 64;
  f32x4 acc[4][4] = {};

  auto STAGE = [&](int k0_, int bufoff_) {
    #pragma unroll
    for (int i=0;i<4;++i) {
      const int qq = i*256 + t;                 // 0..1023 -> 16KB tile
      const unsigned o = (unsigned)qq*16u;
      const int r = o >> 7, sp = (o >> 4) & 7;
      const int sd = sp ^ (r & 7);              // logical slot stored here
      const size_t koff = (size_t)k0_ + (sd & 3)*8;
      const ushort_t* srcA = ((sd<4)?Ahi:Alo) + (size_t)(row0+r)*K + koff;
      const ushort_t* srcB = ((sd<4)?Bhi:Blo) + (size_t)(col0+r)*K + koff;
      char* du = lds + bufoff_ + (o - (unsigned)lane*16u);  // wave-uniform base
      gload16(srcA, du);
      gload16(srcB, du + 16384);
    }
  };

  STAGE(0, 0);
  __syncthreads();               // drains vmcnt: buf0 ready
  int cur = 0;
  for (int k0 = 0; k0 < K; k0 += 32) {
    const int nxt = cur ^ 1;
    if (k0 + 32 < K) STAGE(k0 + 32, nxt*32768);   // prefetch next tile
    const char* abase = lds + cur*32768;
    const char* bbase = abase + 16384;
    s16x8 ah[4], al_[4], bh[4], bl[4];
    #pragma unroll
    for (int mf=0; mf<4; ++mf) {
      const int r = wm + mf*16 + l15;
      const char* rp = abase + r*128;
      ah[mf]  = *(const s16x8*)(rp + ((g ^ (r&7))*16));
      al_[mf] = *(const s16x8*)(rp + (((4|g) ^ (r&7))*16));
    }
    #pragma unroll
    for (int nf=0; nf<4; ++nf) {
      const int r = wn + nf*16 + l15;
      const char* rp = bbase + r*128;
      bh[nf] = *(const s16x8*)(rp + ((g ^ (r&7))*16));
      bl[nf] = *(const s16x8*)(rp + (((4|g) ^ (r&7))*16));
    }
    #pragma unroll
    for (int mf=0; mf<4; ++mf)
      #pragma unroll
      for (int nf=0; nf<4; ++nf) {
        f32x4 c = acc[mf][nf];
        c = MFMA16(ah[mf],  bh[nf], c);
        c = MFMA16(ah[mf],  bl[nf], c);
        c = MFMA16(al_[mf], bh[nf], c);
        acc[mf][nf] = c;
      }
    __syncthreads();             // drains vmcnt (prefetch) + lgkm; flip
    cur = nxt;
  }

  #pragma unroll
  for (int mf=0; mf<4; ++mf) {
    const int rr = row0 + wm + mf*16 + g*4;
    #pragma unroll
    for (int nf=0; nf<4; ++nf) {
      const int cc = col0 + wn + nf*16 + l15;
      if constexpr (EPI == 5) {
        if (col0 < 4096) {                       // q|k region (block-uniform)
          #pragma unroll
          for (int j=0;j<4;++j) {
            ushort_t hh, ll; split2(acc[mf][nf][j], hh, ll);
            const size_t idx = (size_t)(rr+j)*QKS + cc;
            ohi[idx] = hh; olo[idx] = ll;
          }
        } else {                                 // v region -> transposed [d][s]
          const int dd = cc - 4096;
          u16x4 hv, lv;
          #pragma unroll
          for (int j=0;j<4;++j) {
            ushort_t hh, ll; split2(acc[mf][nf][j], hh, ll);
            hv[j] = hh; lv[j] = ll;
          }
          *(u16x4*)(ohi2 + (size_t)dd*SEQ + rr) = hv;
          *(u16x4*)(olo2 + (size_t)dd*SEQ + rr) = lv;
        }
      } else {
        #pragma unroll
        for (int j=0;j<4;++j) {
          const size_t idx = (size_t)(rr+j)*N + cc;
          float v = acc[mf][nf][j];
          if constexpr (EPI == 2) {
            outf[idx] = resid[idx] + v + bias[cc];
          } else if constexpr (EPI == 3) {
            float u = v + bias[cc];
            float gg = 0.5f*u*(1.0f + tanhf(0.7978845608028654f*(u + 0.044715f*u*u*u)));
            ushort_t hh, ll; split2(gg, hh, ll);
            ohi[idx]=hh; olo[idx]=ll;
          } else {  // EPI == 4
            outf[idx] = resid[idx] + v;
          }
        }
      }
    }
  }
}

// ---------------------------- flash attention ------------------------------
// Per-batch: grid (qb=16, head=16), 512 thr (8 waves x 16 q-rows).
// Q|K in fused buffer [SEQ][QKS=4096] (q cols 0..2047, k cols 2048..4095).
// V^T per-head [2048 d][SEQ s].
// K tile LDS: [64][256B] (16 slots, low-3-bit XOR swizzle), hi @0, lo @16384.
// V^T tile:   [128][128B] (8 slots, XOR swizzle),           hi @32768, lo @49152.
__global__ __launch_bounds__(512)
void attn_fwd(const ushort_t* __restrict__ QKhi, const ushort_t* __restrict__ QKlo,
              const ushort_t* __restrict__ VThi, const ushort_t* __restrict__ VTlo,
              ushort_t* __restrict__ Chi, ushort_t* __restrict__ Clo)
{
  __shared__ __align__(16) char kv[65536];
  __shared__ __align__(16) float plds[8][16][68];
  const int qb = blockIdx.x, hh_ = blockIdx.y;
  const int t = threadIdx.x, lane = t & 63, w = t >> 6;
  const int l15 = lane & 15, g = lane >> 4;
  const int qrow = qb*128 + w*16 + l15;
  const size_t qbase = (size_t)qrow*QKS + hh_*HD;
  s16x8 qh[4], ql[4];
  #pragma unroll
  for (int ks=0; ks<4; ++ks) {
    qh[ks] = *(const s16x8*)(QKhi + qbase + ks*32 + g*8);
    ql[ks] = *(const s16x8*)(QKlo + qbase + ks*32 + g*8);
  }
  f32x4 ctx[8] = {};
  float ms[4], ls[4];
  #pragma unroll
  for (int j=0;j<4;++j){ ms[j] = -__builtin_inff(); ls[j] = 0.f; }
  const int ntiles = qb*2 + 2;
  const float scale = 0.08838834764831844f;
  for (int kt=0; kt<ntiles; ++kt) {
    { // stage K tile (hi/lo) + V^T tile (hi/lo)
      const size_t kbase = (size_t)(kt*64)*QKS + 2048 + hh_*HD;
      #pragma unroll
      for (int i=0;i<2;++i) {
        const int qq = i*512 + t;
        const unsigned o = (unsigned)qq*16u;
        const int r = o >> 8, sp = (o >> 4) & 15;
        const int sd = (sp & 8) | ((sp & 7) ^ (r & 7));
        char* du = kv + (o - (unsigned)lane*16u);
        gload16(QKhi + kbase + (size_t)r*QKS + sd*8, du);
        gload16(QKlo + kbase + (size_t)r*QKS + sd*8, du + 16384);
      }
      const size_t vbase = (size_t)hh_*HD*SEQ + (size_t)kt*64;
      #pragma unroll
      for (int i=0;i<2;++i) {
        const int qq = i*512 + t;
        const unsigned o = (unsigned)qq*16u;
        const int r = o >> 7, sp = (o >> 4) & 7;
        const int sd = sp ^ (r & 7);
        char* du = kv + 32768 + (o - (unsigned)lane*16u);
        gload16(VThi + vbase + (size_t)r*SEQ + sd*8, du);
        gload16(VTlo + vbase + (size_t)r*SEQ + sd*8, du + 16384);
      }
    }
    __syncthreads();
    // QK^T (3-term split)
    f32x4 sc[4];
    #pragma unroll
    for (int nf=0; nf<4; ++nf) {
      f32x4 s = {};
      const int rB = nf*16 + l15;
      const char* rp = kv + rB*256;
      #pragma unroll
      for (int ks=0; ks<4; ++ks) {
        const int slot = ks*4 + g;
        const int ph = (slot & 8) | ((slot & 7) ^ (rB & 7));
        s16x8 kbh = *(const s16x8*)(rp + ph*16);
        s16x8 kbl = *(const s16x8*)(rp + 16384 + ph*16);
        s = MFMA16(qh[ks], kbh, s);
        s = MFMA16(qh[ks], kbl, s);
        s = MFMA16(ql[ks], kbh, s);
      }
      sc[nf] = s;
    }
    // scale + causal mask (C/D: col = l15, row = g*4+j)
    const int rowq = qb*128 + w*16 + g*4;
    #pragma unroll
    for (int nf=0; nf<4; ++nf) {
      const int col = kt*64 + nf*16 + l15;
      #pragma unroll
      for (int j=0;j<4;++j) {
        float v = sc[nf][j]*scale;
        sc[nf][j] = (col > rowq + j) ? -__builtin_inff() : v;
      }
    }
    // online softmax (reduce over l15)
    float tm[4], al[4], mnu[4], ts[4];
    #pragma unroll
    for (int j=0;j<4;++j) {
      float m = fmaxf(fmaxf(sc[0][j], sc[1][j]), fmaxf(sc[2][j], sc[3][j]));
      #pragma unroll
      for (int d=1; d<16; d<<=1) m = fmaxf(m, __shfl_xor(m, d, 64));
      tm[j] = m;
    }
    #pragma unroll
    for (int j=0;j<4;++j) {
      const float mo = ms[j];
      const float mn = fmaxf(mo, tm[j]);
      const float mu = fmaxf(mn, -1e30f);
      al[j] = expf(mo - mu);
      mnu[j] = mu; ms[j] = mn; ts[j] = 0.f;
    }
    #pragma unroll
    for (int nf=0; nf<4; ++nf)
      #pragma unroll
      for (int j=0;j<4;++j) {
        float p = expf(sc[nf][j] - mnu[j]);
        sc[nf][j] = p;
        ts[j] += p;
      }
    #pragma unroll
    for (int j=0;j<4;++j) {
      #pragma unroll
      for (int d=1; d<16; d<<=1) ts[j] += __shfl_xor(ts[j], d, 64);
      ls[j] = ls[j]*al[j] + ts[j];
    }
    #pragma unroll
    for (int nf2=0; nf2<8; ++nf2)
      #pragma unroll
      for (int j=0;j<4;++j) ctx[nf2][j] *= al[j];
    // P -> LDS (wave-private), then PV
    #pragma unroll
    for (int nf=0; nf<4; ++nf)
      #pragma unroll
      for (int j=0;j<4;++j)
        plds[w][g*4+j][nf*16+l15] = sc[nf][j];
    asm volatile("s_waitcnt lgkmcnt(0)" ::: "memory");
    __builtin_amdgcn_sched_barrier(0);
    #pragma unroll
    for (int ks2=0; ks2<2; ++ks2) {
      const float* pr = &plds[w][l15][ks2*32 + g*8];
      f32x4 p0 = *(const f32x4*)pr;
      f32x4 p1 = *(const f32x4*)(pr + 4);
      s16x8 ph8, pl8;
      #pragma unroll
      for (int e=0;e<4;++e) {
        ushort_t h1_, l1_; split2(p0[e], h1_, l1_);
        ph8[e] = (short)h1_; pl8[e] = (short)l1_;
        ushort_t h2_, l2_; split2(p1[e], h2_, l2_);
        ph8[e+4] = (short)h2_; pl8[e+4] = (short)l2_;
      }
      #pragma unroll
      for (int nf2=0; nf2<8; ++nf2) {
        const int rV = nf2*16 + l15;
        const int ph_ = (ks2*4 + g) ^ (rV & 7);
        const char* vp = kv + 32768 + rV*128 + ph_*16;
        s16x8 vbh = *(const s16x8*)vp;
        s16x8 vbl = *(const s16x8*)(vp + 16384);
        ctx[nf2] = MFMA16(ph8, vbh, ctx[nf2]);
        ctx[nf2] = MFMA16(ph8, vbl, ctx[nf2]);
        ctx[nf2] = MFMA16(pl8, vbh, ctx[nf2]);
      }
    }
    __syncthreads();
  }
  float rl[4];
  #pragma unroll
  for (int j=0;j<4;++j) rl[j] = 1.f / ls[j];
  #pragma unroll
  for (int nf2=0; nf2<8; ++nf2) {
    #pragma unroll
    for (int j=0;j<4;++j) {
      float v = ctx[nf2][j]*rl[j];
      const size_t idx = (size_t)(qb*128 + w*16 + g*4 + j)*EMBED
                       + hh_*HD + nf2*16 + l15;
      ushort_t hh, ll; split2(v, hh, ll);
      Chi[idx] = hh; Clo[idx] = ll;
    }
  }
}

// ------------------------------- launcher ----------------------------------
extern "C" void kernel_launch(void* const* d_in, const int* in_sizes, int n_in,
                              void* d_out, int out_size, void* d_ws, size_t ws_size,
                              hipStream_t stream)
{
  (void)in_sizes; (void)n_in; (void)out_size; (void)ws_size;
  const float* x    = (const float*)d_in[0];
  const float* wq   = (const float*)d_in[1];
  const float* wk   = (const float*)d_in[2];
  const float* wv   = (const float*)d_in[3];
  const float* wo   = (const float*)d_in[4];
  const float* bo   = (const float*)d_in[5];
  const float* w1   = (const float*)d_in[6];
  const float* b1   = (const float*)d_in[7];
  const float* w2   = (const float*)d_in[8];
  const float* b2   = (const float*)d_in[9];
  const float* ln1s = (const float*)d_in[10];
  const float* ln1h = (const float*)d_in[11];
  const float* ln2s = (const float*)d_in[12];
  const float* ln2h = (const float*)d_in[13];
  float* dout = (float*)d_out;

  char* ws = (char*)d_ws;
  const size_t MB = 1ull << 20;
  // phase A
  ushort_t* qkvT_hi = (ushort_t*)(ws +   0*MB);  // [6144][2048] 24MB
  ushort_t* qkvT_lo = (ushort_t*)(ws +  24*MB);
  ushort_t* woT_hi  = (ushort_t*)(ws +  48*MB);  // [2048][2048] 8MB
  ushort_t* woT_lo  = (ushort_t*)(ws +  56*MB);
  ushort_t* h1_hi   = (ushort_t*)(ws +  64*MB);  // [8192][2048] 32MB -> ctx
  ushort_t* h1_lo   = (ushort_t*)(ws +  96*MB);
  ushort_t* qk_hi   = (ushort_t*)(ws + 128*MB);  // [2048][4096] 16MB
  ushort_t* qk_lo   = (ushort_t*)(ws + 144*MB);
  ushort_t* vt_hi   = (ushort_t*)(ws + 160*MB);  // [2048][2048] 8MB
  ushort_t* vt_lo   = (ushort_t*)(ws + 168*MB);
  // phase B (aliases, all dead by then)
  ushort_t* h2_hi   = (ushort_t*)(ws +   0*MB);  // [8192][2048] 32MB
  ushort_t* h2_lo   = (ushort_t*)(ws +  32*MB);
  ushort_t* h3_hi   = (ushort_t*)(ws +  64*MB);  // [8192][2048] 32MB
  ushort_t* h3_lo   = (ushort_t*)(ws +  96*MB);
  ushort_t* wT_hi   = (ushort_t*)(ws + 128*MB);  // [2048][2048] 8MB
  ushort_t* wT_lo   = (ushort_t*)(ws + 136*MB);

  // prep: weight transposes + LN1 (full M)
  wtrans_split<<<dim3(64,64), 256, 0, stream>>>(wq, EMBED, EMBED, qkvT_hi,            qkvT_lo);
  wtrans_split<<<dim3(64,64), 256, 0, stream>>>(wk, EMBED, EMBED, qkvT_hi + 2048*2048, qkvT_lo + 2048*2048);
  wtrans_split<<<dim3(64,64), 256, 0, stream>>>(wv, EMBED, EMBED, qkvT_hi + 4096*2048, qkvT_lo + 4096*2048);
  wtrans_split<<<dim3(64,64), 256, 0, stream>>>(wo, EMBED, EMBED, woT_hi, woT_lo);
  ln_split<<<NROWS, 256, 0, stream>>>(x, ln1s, ln1h, h1_hi, h1_lo);

  // per batch: fused QKV projection + flash attention (ctx overwrites h1_b)
  for (int b = 0; b < BATCH; ++b) {
    const size_t so = (size_t)b * SEQ * EMBED;
    gemm_split<5><<<dim3(16,48), 256, 0, stream>>>(
        h1_hi + so, h1_lo + so, qkvT_hi, qkvT_lo,
        SEQ, 6144, EMBED, nullptr, qk_hi, qk_lo, vt_hi, vt_lo, nullptr, nullptr);
    attn_fwd<<<dim3(16,16), 512, 0, stream>>>(qk_hi, qk_lo, vt_hi, vt_lo,
                                              h1_hi + so, h1_lo + so);
  }

  // x2 = x + ctx@wo + bo  -> d_out  (full M, grid 1024)
  gemm_split<2><<<dim3(64,16), 256, 0, stream>>>(
      h1_hi, h1_lo, woT_hi, woT_lo, NROWS, EMBED, EMBED,
      dout, nullptr, nullptr, nullptr, nullptr, bo, x);

  // LN2: d_out -> h2 (overwrites qkvT/woT, dead)
  ln_split<<<NROWS, 256, 0, stream>>>(dout, ln2s, ln2h, h2_hi, h2_lo);

  // FFN chunked over FF dim; accumulate into d_out in place
  for (int c = 0; c < 4; ++c) {
    // w1 chunk cols [c*2048, (c+1)*2048) -> w1Tc [2048][2048]
    wtrans_split<<<dim3(64,64), 256, 0, stream>>>(w1 + c*2048, FFDIM, EMBED,
                                                  wT_hi, wT_lo);
    // h3c = gelu(h2 @ w1c + b1c)   (grid 1024)
    gemm_split<3><<<dim3(64,16), 256, 0, stream>>>(
        h2_hi, h2_lo, wT_hi, wT_lo, NROWS, EMBED, EMBED,
        nullptr, h3_hi, h3_lo, nullptr, nullptr, b1 + c*2048, nullptr);
    // w2 chunk rows [c*2048, (c+1)*2048) -> w2Tc [2048][2048]
    wtrans_split<<<dim3(64,64), 256, 0, stream>>>(w2 + (size_t)c*2048*EMBED,
                                                  EMBED, 2048, wT_hi, wT_lo);
    // d_out += h3c @ w2c (+ b2 on first chunk)   (grid 1024)
    if (c == 0)
      gemm_split<2><<<dim3(64,16), 256, 0, stream>>>(
          h3_hi, h3_lo, wT_hi, wT_lo, NROWS, EMBED, 2048,
          dout, nullptr, nullptr, nullptr, nullptr, b2, dout);
    else
      gemm_split<4><<<dim3(64,16), 256, 0, stream>>>(
          h3_hi, h3_lo, wT_hi, wT_lo, NROWS, EMBED, 2048,
          dout, nullptr, nullptr, nullptr, nullptr, nullptr, dout);
  }
}

// Round 5
// 3025.231 us; speedup vs baseline: 1.4871x; 1.1493x over previous
//
#include <hip/hip_runtime.h>
#include <stdint.h>

// ---------------------------------------------------------------------------
// TransformerBlock on MI355X (gfx950) — R5: 256x256 GEMM tile (8 waves, BK=32),
// 2-barrier dbuf loop kept from R4 (proven), hoisted staging pointers.
// fp32 in/out, error-compensated bf16 ("3xBF16" split) on MFMA:
//   x = hi + lo (bf16);  A@B ~= Ah@Bh + Ah@Bl + Al@Bh   (rel err ~2^-17)
// GEMM B-operands stored [N][K] (k-contiguous). LDS rows: 128B = 8x16B slots
// (0-3 hi k0..31, 4-7 lo), physically at slot^(row&7) via pre-swizzled global
// sources (global_load_lds writes linearly, base + lane*16).
//
// Arena (<=176 MB, proven good):
//  phase A: [0,48) wqkvT | [48,64) woT | [64,128) h1->ctx |
//           [128,160) qk (stride 4096) | [160,176) vT
//  phase B: [0,64) h2 | [64,128) h3 chunk | [128,144) w1Tc | [144,160) w2Tc
//  x2 lives in d_out (O-proj writes, LN2 reads, FFN2 accumulates in place).
// ---------------------------------------------------------------------------

#define EMBED 2048
#define SEQ   2048
#define BATCH 4
#define NROWS (BATCH*SEQ)
#define FFDIM 8192
#define HEADS 16
#define HD    128
#define QKS   4096   // row stride of fused q|k buffer

typedef unsigned short ushort_t;
typedef float f32x4 __attribute__((ext_vector_type(4)));
typedef short s16x8 __attribute__((ext_vector_type(8)));
typedef ushort_t u16x4 __attribute__((ext_vector_type(4)));

__device__ __forceinline__ ushort_t f2bf(float f) {
  unsigned u = __builtin_bit_cast(unsigned, f);
  u += 0x7fffu + ((u >> 16) & 1u);
  return (ushort_t)(u >> 16);
}
__device__ __forceinline__ float bf2f(ushort_t h) {
  unsigned u = ((unsigned)h) << 16;
  return __builtin_bit_cast(float, u);
}
__device__ __forceinline__ void split2(float f, ushort_t& hi, ushort_t& lo) {
  hi = f2bf(f);
  lo = f2bf(f - bf2f(hi));
}

#define MFMA16(a,b,c) __builtin_amdgcn_mfma_f32_16x16x32_bf16((a),(b),(c),0,0,0)

__device__ __forceinline__ void gload16(const void* g, void* l) {
  __builtin_amdgcn_global_load_lds((const __attribute__((address_space(1))) void*)g,
                                   (__attribute__((address_space(3))) void*)l,
                                   16, 0, 0);
}

// --------------------------- LayerNorm -> hi/lo ----------------------------
__global__ __launch_bounds__(256)
void ln_split(const float* __restrict__ x, const float* __restrict__ sc,
              const float* __restrict__ sh, ushort_t* __restrict__ hi,
              ushort_t* __restrict__ lo)
{
  __shared__ float rs[4], rq[4];
  const int row = blockIdx.x, t = threadIdx.x;
  const int lane = t & 63, w = t >> 6;
  const float* xr = x + (size_t)row * EMBED;
  f32x4 a = *(const f32x4*)(xr + t*4);
  f32x4 b = *(const f32x4*)(xr + 1024 + t*4);
  float s = 0.f, q = 0.f;
  #pragma unroll
  for (int e=0;e<4;++e){ s += a[e]+b[e]; q += a[e]*a[e]+b[e]*b[e]; }
  #pragma unroll
  for (int m=1;m<64;m<<=1){ s += __shfl_xor(s,m,64); q += __shfl_xor(q,m,64); }
  if (lane==0){ rs[w]=s; rq[w]=q; }
  __syncthreads();
  s = rs[0]+rs[1]+rs[2]+rs[3];
  q = rq[0]+rq[1]+rq[2]+rq[3];
  const float mean = s * (1.f/EMBED);
  const float var  = fmaxf(q*(1.f/EMBED) - mean*mean, 0.f);
  const float rstd = rsqrtf(var + 1e-5f);
  #pragma unroll
  for (int half=0; half<2; ++half) {
    const int c0 = half*1024 + t*4;
    f32x4 v = half ? b : a;
    #pragma unroll
    for (int e=0;e<4;++e) {
      float o = sc[c0+e]*((v[e]-mean)*rstd) + sh[c0+e];
      ushort_t hh, ll; split2(o, hh, ll);
      hi[(size_t)row*EMBED + c0+e] = hh;
      lo[(size_t)row*EMBED + c0+e] = ll;
    }
  }
}

// ------- W (k,n) at W[k*ldW+n] -> T [n][K] hi/lo bf16; grid (N/32, K/32) ----
__global__ __launch_bounds__(256)
void wtrans_split(const float* __restrict__ W, int ldW, int K,
                  ushort_t* __restrict__ Thi, ushort_t* __restrict__ Tlo)
{
  __shared__ float tile[32][33];
  const int n0 = blockIdx.x*32, k0 = blockIdx.y*32;
  const int tx = threadIdx.x & 31, ty = threadIdx.x >> 5;
  #pragma unroll
  for (int i=0;i<4;++i)
    tile[ty + i*8][tx] = W[(size_t)(k0 + ty + i*8)*ldW + n0 + tx];
  __syncthreads();
  #pragma unroll
  for (int i=0;i<4;++i) {
    const int nl = ty + i*8;
    float v = tile[tx][nl];
    ushort_t h, l; split2(v, h, l);
    const size_t idx = (size_t)(n0 + nl)*K + k0 + tx;
    Thi[idx] = h; Tlo[idx] = l;
  }
}

// -- dual transpose (w1 chunk + w2 chunk) in one dispatch; grid (64,64,2) ----
__global__ __launch_bounds__(256)
void wtrans2_split(const float* __restrict__ W1, int ldW1,
                   const float* __restrict__ W2, int ldW2, int K,
                   ushort_t* __restrict__ T1hi, ushort_t* __restrict__ T1lo,
                   ushort_t* __restrict__ T2hi, ushort_t* __restrict__ T2lo)
{
  __shared__ float tile[32][33];
  const float* W = blockIdx.z ? W2 : W1;
  const int ldW = blockIdx.z ? ldW2 : ldW1;
  ushort_t* Thi = blockIdx.z ? T2hi : T1hi;
  ushort_t* Tlo = blockIdx.z ? T2lo : T1lo;
  const int n0 = blockIdx.x*32, k0 = blockIdx.y*32;
  const int tx = threadIdx.x & 31, ty = threadIdx.x >> 5;
  #pragma unroll
  for (int i=0;i<4;++i)
    tile[ty + i*8][tx] = W[(size_t)(k0 + ty + i*8)*ldW + n0 + tx];
  __syncthreads();
  #pragma unroll
  for (int i=0;i<4;++i) {
    const int nl = ty + i*8;
    float v = tile[tx][nl];
    ushort_t h, l; split2(v, h, l);
    const size_t idx = (size_t)(n0 + nl)*K + k0 + tx;
    Thi[idx] = h; Tlo[idx] = l;
  }
}

// ------------------------------ split GEMM ---------------------------------
// C[M,N] = A[M,K] @ B^T (B stored [N][K]), 3-term bf16 split, fp32 acc.
// Tile 256x256, BK=32, 512 thr = 8 waves (2 rows x 4 cols, each 128x64).
// Double-buffered LDS (2 x 64KB), STAGE(next) before compute(cur), one
// __syncthreads per iter. Staging pointers hoisted (advance 64B per K-step).
// EPI: 2 = resid+bias -> fp32; 3 = gelu(v+bias) -> hi/lo bf16;
//      4 = resid (no bias) -> fp32; 5 = QKV fused (qk strided / v transposed).
template<int EPI>
__global__ __launch_bounds__(512, 2)
void gemm_split(const ushort_t* __restrict__ Ahi, const ushort_t* __restrict__ Alo,
                const ushort_t* __restrict__ Bhi, const ushort_t* __restrict__ Blo,
                int M, int N, int K,
                float* __restrict__ outf,
                ushort_t* __restrict__ ohi, ushort_t* __restrict__ olo,
                ushort_t* __restrict__ ohi2, ushort_t* __restrict__ olo2,
                const float* __restrict__ bias, const float* __restrict__ resid)
{
  __shared__ __align__(16) char lds[131072];  // buf: A 32KB @0, B 32KB @32768
  const int t = threadIdx.x, lane = t & 63;
  const int wid = t >> 6;
  const int l15 = lane & 15, g = lane >> 4;
  const int row0 = blockIdx.x * 256, col0 = blockIdx.y * 256;
  const int wm = (wid >> 2) * 128, wn = (wid & 3) * 64;

  // hoisted staging sources: thread's 4 A-slots + 4 B-slots (advance 32 elts/step)
  const ushort_t* pA[4]; const ushort_t* pB[4]; int duo[4];
  #pragma unroll
  for (int i=0;i<4;++i) {
    const int qq = i*512 + t;                 // 0..2047 -> 32KB tile
    const unsigned o = (unsigned)qq*16u;
    const int r = o >> 7, sp = (o >> 4) & 7;
    const int sd = sp ^ (r & 7);              // logical slot stored at sp
    const size_t koff = (size_t)((sd & 3)*8);
    pA[i] = ((sd<4)?Ahi:Alo) + (size_t)(row0+r)*K + koff;
    pB[i] = ((sd<4)?Bhi:Blo) + (size_t)(col0+r)*K + koff;
    duo[i] = i*8192 + wid*1024;               // o - lane*16 (wave-uniform)
  }
  auto STAGE = [&](int bufoff_) {
    #pragma unroll
    for (int i=0;i<4;++i) {
      char* du = lds + bufoff_ + duo[i];
      gload16(pA[i], du);
      gload16(pB[i], du + 32768);
      pA[i] += 32; pB[i] += 32;
    }
  };

  f32x4 acc[8][4] = {};
  STAGE(0);
  __syncthreads();               // drains vmcnt: buf0 ready
  int cur = 0;
  const int nstep = K >> 5;
  for (int ks = 0; ks < nstep; ++ks) {
    const int nxt = cur ^ 1;
    if (ks + 1 < nstep) STAGE(nxt*65536);   // prefetch next K-tile
    const char* abase = lds + cur*65536;
    const char* bbase = abase + 32768;
    s16x8 bh[4], bl[4];
    #pragma unroll
    for (int nf=0; nf<4; ++nf) {
      const int r = wn + nf*16 + l15;
      const char* rp = bbase + r*128;
      bh[nf] = *(const s16x8*)(rp + ((g ^ (r&7))*16));
      bl[nf] = *(const s16x8*)(rp + (((4|g) ^ (r&7))*16));
    }
    #pragma unroll
    for (int mf=0; mf<8; ++mf) {
      const int r = wm + mf*16 + l15;
      const char* rp = abase + r*128;
      s16x8 ah  = *(const s16x8*)(rp + ((g ^ (r&7))*16));
      s16x8 al_ = *(const s16x8*)(rp + (((4|g) ^ (r&7))*16));
      #pragma unroll
      for (int nf=0; nf<4; ++nf) {
        f32x4 c = acc[mf][nf];
        c = MFMA16(ah,  bh[nf], c);
        c = MFMA16(ah,  bl[nf], c);
        c = MFMA16(al_, bh[nf], c);
        acc[mf][nf] = c;
      }
    }
    __syncthreads();             // drains vmcnt (prefetch) + lgkm; flip
    cur = nxt;
  }

  #pragma unroll
  for (int mf=0; mf<8; ++mf) {
    const int rr = row0 + wm + mf*16 + g*4;
    #pragma unroll
    for (int nf=0; nf<4; ++nf) {
      const int cc = col0 + wn + nf*16 + l15;
      if constexpr (EPI == 5) {
        if (col0 < 4096) {                       // q|k region (block-uniform)
          #pragma unroll
          for (int j=0;j<4;++j) {
            ushort_t hh, ll; split2(acc[mf][nf][j], hh, ll);
            const size_t idx = (size_t)(rr+j)*QKS + cc;
            ohi[idx] = hh; olo[idx] = ll;
          }
        } else {                                 // v region -> transposed [d][s]
          const int dd = cc - 4096;
          u16x4 hv, lv;
          #pragma unroll
          for (int j=0;j<4;++j) {
            ushort_t hh, ll; split2(acc[mf][nf][j], hh, ll);
            hv[j] = hh; lv[j] = ll;
          }
          *(u16x4*)(ohi2 + (size_t)dd*SEQ + rr) = hv;
          *(u16x4*)(olo2 + (size_t)dd*SEQ + rr) = lv;
        }
      } else {
        #pragma unroll
        for (int j=0;j<4;++j) {
          const size_t idx = (size_t)(rr+j)*N + cc;
          float v = acc[mf][nf][j];
          if constexpr (EPI == 2) {
            outf[idx] = resid[idx] + v + bias[cc];
          } else if constexpr (EPI == 3) {
            float u = v + bias[cc];
            float gg = 0.5f*u*(1.0f + tanhf(0.7978845608028654f*(u + 0.044715f*u*u*u)));
            ushort_t hh, ll; split2(gg, hh, ll);
            ohi[idx]=hh; olo[idx]=ll;
          } else {  // EPI == 4
            outf[idx] = resid[idx] + v;
          }
        }
      }
    }
  }
}

// ---------------------------- flash attention ------------------------------
// Per-batch: grid (qb=16, head=16), 512 thr (8 waves x 16 q-rows).
// Q|K fused buffer [SEQ][QKS=4096] (q cols 0..2047, k cols 2048..4095).
// V^T per-head [2048 d][SEQ s].
// K tile LDS: [64][256B] (16 slots, low-3-bit XOR swizzle), hi @0, lo @16384.
// V^T tile:   [128][128B] (8 slots, XOR swizzle),           hi @32768, lo @49152.
__global__ __launch_bounds__(512)
void attn_fwd(const ushort_t* __restrict__ QKhi, const ushort_t* __restrict__ QKlo,
              const ushort_t* __restrict__ VThi, const ushort_t* __restrict__ VTlo,
              ushort_t* __restrict__ Chi, ushort_t* __restrict__ Clo)
{
  __shared__ __align__(16) char kv[65536];
  __shared__ __align__(16) float plds[8][16][68];
  const int qb = blockIdx.x, hh_ = blockIdx.y;
  const int t = threadIdx.x, lane = t & 63, w = t >> 6;
  const int l15 = lane & 15, g = lane >> 4;
  const int qrow = qb*128 + w*16 + l15;
  const size_t qbase = (size_t)qrow*QKS + hh_*HD;
  s16x8 qh[4], ql[4];
  #pragma unroll
  for (int ks=0; ks<4; ++ks) {
    qh[ks] = *(const s16x8*)(QKhi + qbase + ks*32 + g*8);
    ql[ks] = *(const s16x8*)(QKlo + qbase + ks*32 + g*8);
  }
  f32x4 ctx[8] = {};
  float ms[4], ls[4];
  #pragma unroll
  for (int j=0;j<4;++j){ ms[j] = -__builtin_inff(); ls[j] = 0.f; }
  const int ntiles = qb*2 + 2;
  const float scale = 0.08838834764831844f;
  for (int kt=0; kt<ntiles; ++kt) {
    { // stage K tile (hi/lo) + V^T tile (hi/lo)
      const size_t kbase = (size_t)(kt*64)*QKS + 2048 + hh_*HD;
      #pragma unroll
      for (int i=0;i<2;++i) {
        const int qq = i*512 + t;
        const unsigned o = (unsigned)qq*16u;
        const int r = o >> 8, sp = (o >> 4) & 15;
        const int sd = (sp & 8) | ((sp & 7) ^ (r & 7));
        char* du = kv + (o - (unsigned)lane*16u);
        gload16(QKhi + kbase + (size_t)r*QKS + sd*8, du);
        gload16(QKlo + kbase + (size_t)r*QKS + sd*8, du + 16384);
      }
      const size_t vbase = (size_t)hh_*HD*SEQ + (size_t)kt*64;
      #pragma unroll
      for (int i=0;i<2;++i) {
        const int qq = i*512 + t;
        const unsigned o = (unsigned)qq*16u;
        const int r = o >> 7, sp = (o >> 4) & 7;
        const int sd = sp ^ (r & 7);
        char* du = kv + 32768 + (o - (unsigned)lane*16u);
        gload16(VThi + vbase + (size_t)r*SEQ + sd*8, du);
        gload16(VTlo + vbase + (size_t)r*SEQ + sd*8, du + 16384);
      }
    }
    __syncthreads();
    // QK^T (3-term split)
    f32x4 sc[4];
    #pragma unroll
    for (int nf=0; nf<4; ++nf) {
      f32x4 s = {};
      const int rB = nf*16 + l15;
      const char* rp = kv + rB*256;
      #pragma unroll
      for (int ks=0; ks<4; ++ks) {
        const int slot = ks*4 + g;
        const int ph = (slot & 8) | ((slot & 7) ^ (rB & 7));
        s16x8 kbh = *(const s16x8*)(rp + ph*16);
        s16x8 kbl = *(const s16x8*)(rp + 16384 + ph*16);
        s = MFMA16(qh[ks], kbh, s);
        s = MFMA16(qh[ks], kbl, s);
        s = MFMA16(ql[ks], kbh, s);
      }
      sc[nf] = s;
    }
    // scale + causal mask (C/D: col = l15, row = g*4+j)
    const int rowq = qb*128 + w*16 + g*4;
    #pragma unroll
    for (int nf=0; nf<4; ++nf) {
      const int col = kt*64 + nf*16 + l15;
      #pragma unroll
      for (int j=0;j<4;++j) {
        float v = sc[nf][j]*scale;
        sc[nf][j] = (col > rowq + j) ? -__builtin_inff() : v;
      }
    }
    // online softmax (reduce over l15)
    float tm[4], al[4], mnu[4], ts[4];
    #pragma unroll
    for (int j=0;j<4;++j) {
      float m = fmaxf(fmaxf(sc[0][j], sc[1][j]), fmaxf(sc[2][j], sc[3][j]));
      #pragma unroll
      for (int d=1; d<16; d<<=1) m = fmaxf(m, __shfl_xor(m, d, 64));
      tm[j] = m;
    }
    #pragma unroll
    for (int j=0;j<4;++j) {
      const float mo = ms[j];
      const float mn = fmaxf(mo, tm[j]);
      const float mu = fmaxf(mn, -1e30f);
      al[j] = expf(mo - mu);
      mnu[j] = mu; ms[j] = mn; ts[j] = 0.f;
    }
    #pragma unroll
    for (int nf=0; nf<4; ++nf)
      #pragma unroll
      for (int j=0;j<4;++j) {
        float p = expf(sc[nf][j] - mnu[j]);
        sc[nf][j] = p;
        ts[j] += p;
      }
    #pragma unroll
    for (int j=0;j<4;++j) {
      #pragma unroll
      for (int d=1; d<16; d<<=1) ts[j] += __shfl_xor(ts[j], d, 64);
      ls[j] = ls[j]*al[j] + ts[j];
    }
    #pragma unroll
    for (int nf2=0; nf2<8; ++nf2)
      #pragma unroll
      for (int j=0;j<4;++j) ctx[nf2][j] *= al[j];
    // P -> LDS (wave-private), then PV
    #pragma unroll
    for (int nf=0; nf<4; ++nf)
      #pragma unroll
      for (int j=0;j<4;++j)
        plds[w][g*4+j][nf*16+l15] = sc[nf][j];
    asm volatile("s_waitcnt lgkmcnt(0)" ::: "memory");
    __builtin_amdgcn_sched_barrier(0);
    #pragma unroll
    for (int ks2=0; ks2<2; ++ks2) {
      const float* pr = &plds[w][l15][ks2*32 + g*8];
      f32x4 p0 = *(const f32x4*)pr;
      f32x4 p1 = *(const f32x4*)(pr + 4);
      s16x8 ph8, pl8;
      #pragma unroll
      for (int e=0;e<4;++e) {
        ushort_t h1_, l1_; split2(p0[e], h1_, l1_);
        ph8[e] = (short)h1_; pl8[e] = (short)l1_;
        ushort_t h2_, l2_; split2(p1[e], h2_, l2_);
        ph8[e+4] = (short)h2_; pl8[e+4] = (short)l2_;
      }
      #pragma unroll
      for (int nf2=0; nf2<8; ++nf2) {
        const int rV = nf2*16 + l15;
        const int ph_ = (ks2*4 + g) ^ (rV & 7);
        const char* vp = kv + 32768 + rV*128 + ph_*16;
        s16x8 vbh = *(const s16x8*)vp;
        s16x8 vbl = *(const s16x8*)(vp + 16384);
        ctx[nf2] = MFMA16(ph8, vbh, ctx[nf2]);
        ctx[nf2] = MFMA16(ph8, vbl, ctx[nf2]);
        ctx[nf2] = MFMA16(pl8, vbh, ctx[nf2]);
      }
    }
    __syncthreads();
  }
  float rl[4];
  #pragma unroll
  for (int j=0;j<4;++j) rl[j] = 1.f / ls[j];
  #pragma unroll
  for (int nf2=0; nf2<8; ++nf2) {
    #pragma unroll
    for (int j=0;j<4;++j) {
      float v = ctx[nf2][j]*rl[j];
      const size_t idx = (size_t)(qb*128 + w*16 + g*4 + j)*EMBED
                       + hh_*HD + nf2*16 + l15;
      ushort_t hh, ll; split2(v, hh, ll);
      Chi[idx] = hh; Clo[idx] = ll;
    }
  }
}

// ------------------------------- launcher ----------------------------------
extern "C" void kernel_launch(void* const* d_in, const int* in_sizes, int n_in,
                              void* d_out, int out_size, void* d_ws, size_t ws_size,
                              hipStream_t stream)
{
  (void)in_sizes; (void)n_in; (void)out_size; (void)ws_size;
  const float* x    = (const float*)d_in[0];
  const float* wq   = (const float*)d_in[1];
  const float* wk   = (const float*)d_in[2];
  const float* wv   = (const float*)d_in[3];
  const float* wo   = (const float*)d_in[4];
  const float* bo   = (const float*)d_in[5];
  const float* w1   = (const float*)d_in[6];
  const float* b1   = (const float*)d_in[7];
  const float* w2   = (const float*)d_in[8];
  const float* b2   = (const float*)d_in[9];
  const float* ln1s = (const float*)d_in[10];
  const float* ln1h = (const float*)d_in[11];
  const float* ln2s = (const float*)d_in[12];
  const float* ln2h = (const float*)d_in[13];
  float* dout = (float*)d_out;

  char* ws = (char*)d_ws;
  const size_t MB = 1ull << 20;
  // phase A
  ushort_t* qkvT_hi = (ushort_t*)(ws +   0*MB);  // [6144][2048] 24MB
  ushort_t* qkvT_lo = (ushort_t*)(ws +  24*MB);
  ushort_t* woT_hi  = (ushort_t*)(ws +  48*MB);  // [2048][2048] 8MB
  ushort_t* woT_lo  = (ushort_t*)(ws +  56*MB);
  ushort_t* h1_hi   = (ushort_t*)(ws +  64*MB);  // [8192][2048] 32MB -> ctx
  ushort_t* h1_lo   = (ushort_t*)(ws +  96*MB);
  ushort_t* qk_hi   = (ushort_t*)(ws + 128*MB);  // [2048][4096] 16MB
  ushort_t* qk_lo   = (ushort_t*)(ws + 144*MB);
  ushort_t* vt_hi   = (ushort_t*)(ws + 160*MB);  // [2048][2048] 8MB
  ushort_t* vt_lo   = (ushort_t*)(ws + 168*MB);
  // phase B (aliases, all dead by then)
  ushort_t* h2_hi   = (ushort_t*)(ws +   0*MB);  // [8192][2048] 32MB
  ushort_t* h2_lo   = (ushort_t*)(ws +  32*MB);
  ushort_t* h3_hi   = (ushort_t*)(ws +  64*MB);  // [8192][2048] 32MB
  ushort_t* h3_lo   = (ushort_t*)(ws +  96*MB);
  ushort_t* wT_hi   = (ushort_t*)(ws + 128*MB);  // [2048][2048] 8MB
  ushort_t* wT_lo   = (ushort_t*)(ws + 136*MB);
  ushort_t* w2T_hi  = (ushort_t*)(ws + 144*MB);  // [2048][2048] 8MB
  ushort_t* w2T_lo  = (ushort_t*)(ws + 152*MB);

  // prep: weight transposes + LN1 (full M)
  wtrans_split<<<dim3(64,64), 256, 0, stream>>>(wq, EMBED, EMBED, qkvT_hi,             qkvT_lo);
  wtrans_split<<<dim3(64,64), 256, 0, stream>>>(wk, EMBED, EMBED, qkvT_hi + 2048*2048, qkvT_lo + 2048*2048);
  wtrans_split<<<dim3(64,64), 256, 0, stream>>>(wv, EMBED, EMBED, qkvT_hi + 4096*2048, qkvT_lo + 4096*2048);
  wtrans_split<<<dim3(64,64), 256, 0, stream>>>(wo, EMBED, EMBED, woT_hi, woT_lo);
  ln_split<<<NROWS, 256, 0, stream>>>(x, ln1s, ln1h, h1_hi, h1_lo);

  // per batch: fused QKV projection + flash attention (ctx overwrites h1_b)
  for (int b = 0; b < BATCH; ++b) {
    const size_t so = (size_t)b * SEQ * EMBED;
    gemm_split<5><<<dim3(8,24), 512, 0, stream>>>(
        h1_hi + so, h1_lo + so, qkvT_hi, qkvT_lo,
        SEQ, 6144, EMBED, nullptr, qk_hi, qk_lo, vt_hi, vt_lo, nullptr, nullptr);
    attn_fwd<<<dim3(16,16), 512, 0, stream>>>(qk_hi, qk_lo, vt_hi, vt_lo,
                                              h1_hi + so, h1_lo + so);
  }

  // x2 = x + ctx@wo + bo  -> d_out  (grid 256 = 1/CU)
  gemm_split<2><<<dim3(32,8), 512, 0, stream>>>(
      h1_hi, h1_lo, woT_hi, woT_lo, NROWS, EMBED, EMBED,
      dout, nullptr, nullptr, nullptr, nullptr, bo, x);

  // LN2: d_out -> h2 (overwrites qkvT/woT, dead)
  ln_split<<<NROWS, 256, 0, stream>>>(dout, ln2s, ln2h, h2_hi, h2_lo);

  // FFN chunked over FF dim; accumulate into d_out in place
  for (int c = 0; c < 4; ++c) {
    // w1 cols [c*2048..) -> w1Tc ; w2 rows [c*2048..) -> w2Tc  (one dispatch)
    wtrans2_split<<<dim3(64,64,2), 256, 0, stream>>>(
        w1 + c*2048, FFDIM, w2 + (size_t)c*2048*EMBED, EMBED, 2048,
        wT_hi, wT_lo, w2T_hi, w2T_lo);
    // h3c = gelu(h2 @ w1c + b1c)   (grid 256)
    gemm_split<3><<<dim3(32,8), 512, 0, stream>>>(
        h2_hi, h2_lo, wT_hi, wT_lo, NROWS, EMBED, EMBED,
        nullptr, h3_hi, h3_lo, nullptr, nullptr, b1 + c*2048, nullptr);
    // d_out += h3c @ w2c (+ b2 on first chunk)   (grid 256)
    if (c == 0)
      gemm_split<2><<<dim3(32,8), 512, 0, stream>>>(
          h3_hi, h3_lo, w2T_hi, w2T_lo, NROWS, EMBED, 2048,
          dout, nullptr, nullptr, nullptr, nullptr, b2, dout);
    else
      gemm_split<4><<<dim3(32,8), 512, 0, stream>>>(
          h3_hi, h3_lo, w2T_hi, w2T_lo, NROWS, EMBED, 2048,
          dout, nullptr, nullptr, nullptr, nullptr, nullptr, dout);
  }
}